// Round 6
// baseline (164.809 us; speedup 1.0000x reference)
//
#include <hip/hip_runtime.h>

#define FH 50
#define FW 75
#define FC 512
#define NPOOL 7
#define NXCD 8

typedef float f32x4 __attribute__((ext_vector_type(4)));

__device__ __forceinline__ float uniform_f(float x) {
    return __int_as_float(__builtin_amdgcn_readfirstlane(__float_as_int(x)));
}

__global__ __launch_bounds__(128) void roi_pool_kernel(
    const float* __restrict__ fmap,     // (1, FH, FW, FC)
    const float* __restrict__ rois,     // (N, 4) = x1,y1,x2,y2 image coords
    const int*   __restrict__ img_size, // [800, 1200]
    float* __restrict__ out,            // (N, 7, 7, FC)
    int N)
{
    // ---- bijective XCD-chunked swizzle: consecutive w -> same XCD ----
    const int nwg = gridDim.x;
    const int q = nwg / NXCD, r = nwg % NXCD;
    const int xcd = blockIdx.x % NXCD, local = blockIdx.x / NXCD;
    const int w = (xcd < r ? xcd * (q + 1) : r * (q + 1) + (xcd - r) * q) + local;

    const int n  = w / NPOOL;   // ROI index
    const int py = w % NPOOL;   // output row
    if (n >= N) return;

    const float img_h = (float)(img_size[0] - 1);
    const float img_w = (float)(img_size[1] - 1);

    const float rx1 = rois[n * 4 + 0];
    const float ry1 = rois[n * 4 + 1];
    const float rx2 = rois[n * 4 + 2];
    const float ry2 = rois[n * 4 + 3];

    const float fh = (float)(FH - 1);   // 49
    const float fw = (float)(FW - 1);   // 74
    const float stepy = (ry2 - ry1) / img_h * fh * (1.0f / 13.0f);
    const float stepx = (rx2 - rx1) / img_w * fw * (1.0f / 13.0f);
    const float basey = ry1 / img_h * fh;
    const float basex = rx1 / img_w * fw;

    // ---- per-block-uniform coordinate tables, hoisted to SGPRs ----
    // 2 sample rows for this output row
    float wy[2]; float my[2]; int roff[2][2];
    #pragma unroll
    for (int i = 0; i < 2; ++i) {
        const int iy = py * 2 + i;
        const float ys = basey + (float)iy * stepy;
        my[i] = ((ys >= 0.0f) & (ys <= fh)) ? 1.0f : 0.0f;
        const float y0f = floorf(ys);
        wy[i] = uniform_f(ys - y0f);
        my[i] = uniform_f(my[i]);
        int y0 = min(max((int)y0f, 0), FH - 1);
        int y1 = min(y0 + 1, FH - 1);
        roff[i][0] = __builtin_amdgcn_readfirstlane(y0 * (FW * FC));
        roff[i][1] = __builtin_amdgcn_readfirstlane(y1 * (FW * FC));
    }
    // 14 sample cols
    float wx[14]; float mx[14]; int coff[14][2];
    #pragma unroll
    for (int j = 0; j < 14; ++j) {
        const float xs = basex + (float)j * stepx;
        mx[j] = ((xs >= 0.0f) & (xs <= fw)) ? 1.0f : 0.0f;
        const float x0f = floorf(xs);
        wx[j] = uniform_f(xs - x0f);
        mx[j] = uniform_f(mx[j]);
        int x0 = min(max((int)x0f, 0), FW - 1);
        int x1 = min(x0 + 1, FW - 1);
        coff[j][0] = __builtin_amdgcn_readfirstlane(x0 * FC);
        coff[j][1] = __builtin_amdgcn_readfirstlane(x1 * FC);
    }

    const int c4 = threadIdx.x * 4;          // 128 threads * 4 ch = 512
    const float* fm = fmap + c4;
    float* orow = out + ((long)(n * NPOOL + py) * NPOOL) * FC + c4;

    // ---- 7 output pixels, fully unrolled; 16 loads per pixel ----
    #pragma unroll
    for (int px = 0; px < NPOOL; ++px) {
        const int j0 = px * 2, j1 = px * 2 + 1;

        // 16 independent loads (SGPR base + uniform offset + per-thread c4)
        const f32x4 tl00 = *(const f32x4*)(fm + roff[0][0] + coff[j0][0]);
        const f32x4 tr00 = *(const f32x4*)(fm + roff[0][0] + coff[j0][1]);
        const f32x4 bl00 = *(const f32x4*)(fm + roff[0][1] + coff[j0][0]);
        const f32x4 br00 = *(const f32x4*)(fm + roff[0][1] + coff[j0][1]);
        const f32x4 tl01 = *(const f32x4*)(fm + roff[0][0] + coff[j1][0]);
        const f32x4 tr01 = *(const f32x4*)(fm + roff[0][0] + coff[j1][1]);
        const f32x4 bl01 = *(const f32x4*)(fm + roff[0][1] + coff[j1][0]);
        const f32x4 br01 = *(const f32x4*)(fm + roff[0][1] + coff[j1][1]);
        const f32x4 tl10 = *(const f32x4*)(fm + roff[1][0] + coff[j0][0]);
        const f32x4 tr10 = *(const f32x4*)(fm + roff[1][0] + coff[j0][1]);
        const f32x4 bl10 = *(const f32x4*)(fm + roff[1][1] + coff[j0][0]);
        const f32x4 br10 = *(const f32x4*)(fm + roff[1][1] + coff[j0][1]);
        const f32x4 tl11 = *(const f32x4*)(fm + roff[1][0] + coff[j1][0]);
        const f32x4 tr11 = *(const f32x4*)(fm + roff[1][0] + coff[j1][1]);
        const f32x4 bl11 = *(const f32x4*)(fm + roff[1][1] + coff[j1][0]);
        const f32x4 br11 = *(const f32x4*)(fm + roff[1][1] + coff[j1][1]);

        f32x4 m = (f32x4){-INFINITY, -INFINITY, -INFINITY, -INFINITY};

        #define SAMP(TL, TR, BL, BR, I, J)                                   \
        {                                                                     \
            const float wyv = wy[I], wxv = wx[J];                             \
            const float mv  = my[I] * mx[J];                                  \
            f32x4 top = TL + wxv * (TR - TL);                                 \
            f32x4 bot = BL + wxv * (BR - BL);                                 \
            f32x4 v = top + wyv * (bot - top);                                \
            v *= mv;                                                          \
            m.x = fmaxf(m.x, v.x);                                            \
            m.y = fmaxf(m.y, v.y);                                            \
            m.z = fmaxf(m.z, v.z);                                            \
            m.w = fmaxf(m.w, v.w);                                            \
        }

        SAMP(tl00, tr00, bl00, br00, 0, j0)
        SAMP(tl01, tr01, bl01, br01, 0, j1)
        SAMP(tl10, tr10, bl10, br10, 1, j0)
        SAMP(tl11, tr11, bl11, br11, 1, j1)
        #undef SAMP

        __builtin_nontemporal_store(m, (f32x4*)(orow + px * FC));
    }
}

extern "C" void kernel_launch(void* const* d_in, const int* in_sizes, int n_in,
                              void* d_out, int out_size, void* d_ws, size_t ws_size,
                              hipStream_t stream) {
    const float* fmap     = (const float*)d_in[0];
    const float* rois     = (const float*)d_in[1];
    const int*   img_size = (const int*)d_in[2];
    float* out = (float*)d_out;

    const int N = in_sizes[1] / 4;   // rois is (N,4)
    const int blocks = N * NPOOL;    // one block per (roi, output-row)
    roi_pool_kernel<<<blocks, 128, 0, stream>>>(fmap, rois, img_size, out, N);
}